// Round 7
// baseline (1045.723 us; speedup 1.0000x reference)
//
#include <hip/hip_runtime.h>
#include <hip/hip_bf16.h>

#define N_NODES 100000
#define N_EDGES 3200000
#define F_IN    128
#define HID     16
#define N_DRUGS 2000
#define NB      391            // ceil(N_NODES/256)
#define NBUCK   6250           // N_NODES/16 buckets of 16 nodes
#define NCOPY   8              // replicated histogram/cursor copies
#define NHIST   (NBUCK*NCOPY)  // 50000

// ---------------- zero helper ----------------

__global__ void k_zero(int* __restrict__ p, int n) {
    int i = blockIdx.x * blockDim.x + threadIdx.x;
    if (i < n) p[i] = 0;
}

// ---------------- bucket histogram (8 replicated planes) ----------------

__global__ void k_bhist(const int* __restrict__ dst, int* __restrict__ cnt8) {
    int e = blockIdx.x * blockDim.x + threadIdx.x;
    int c = blockIdx.x & (NCOPY - 1);
    if (e < N_EDGES) atomicAdd(&cnt8[c * NBUCK + (dst[e] >> 4)], 1);
}

// ---------------- scan over 50000 logical (bucket-major, copy-minor) ----------------

__global__ void k_bscan(const int* __restrict__ cnt8, int* __restrict__ cur8) {
    __shared__ int s[1024];
    const int PER = 49;  // 1024*49 >= 50000
    int t = threadIdx.x;
    int base = t * PER;
    int sum = 0;
    for (int j = 0; j < PER; ++j) {
        int L = base + j;
        if (L < NHIST) {
            int b = L >> 3, c = L & 7;
            sum += cnt8[c * NBUCK + b];
        }
    }
    s[t] = sum;
    __syncthreads();
    for (int off = 1; off < 1024; off <<= 1) {
        int x = (t >= off) ? s[t - off] : 0;
        __syncthreads();
        s[t] += x;
        __syncthreads();
    }
    int run = s[t] - sum;  // exclusive prefix for this thread's range
    for (int j = 0; j < PER; ++j) {
        int L = base + j;
        if (L < NHIST) {
            int b = L >> 3, c = L & 7;
            int v = cnt8[c * NBUCK + b];
            cur8[c * NBUCK + b] = run;
            run += v;
        }
    }
}

// ---------------- per-bucket meta: start + total count ----------------

__global__ void k_bmeta(const int* __restrict__ cnt8, const int* __restrict__ cur8,
                        int* __restrict__ bstart, int* __restrict__ bcnt) {
    int b = blockIdx.x * blockDim.x + threadIdx.x;
    if (b < NBUCK) {
        bstart[b] = cur8[b];  // copy 0 is first logical segment of bucket b
        int n = 0;
#pragma unroll
        for (int c = 0; c < NCOPY; ++c) n += cnt8[c * NBUCK + b];
        bcnt[b] = n;
    }
}

// ---------------- fill: packed[(pos)] = (src<<4)|(dst&15), bucket-contiguous ----------------

__global__ void k_bfill(const int* __restrict__ src, const int* __restrict__ dst,
                        int* __restrict__ cur8, unsigned int* __restrict__ packed) {
    int e = blockIdx.x * blockDim.x + threadIdx.x;
    int c = blockIdx.x & (NCOPY - 1);
    if (e < N_EDGES) {
        int d = dst[e];
        int pos = atomicAdd(&cur8[c * NBUCK + (d >> 4)], 1);
        packed[pos] = ((unsigned int)src[e] << 4) | (unsigned int)(d & 15);
    }
}

// ---------------- per-bucket degree -> dinv ----------------

__global__ void k_bdeg(const int* __restrict__ bstart, const int* __restrict__ bcnt,
                       const unsigned int* __restrict__ packed, float* __restrict__ dinv) {
    __shared__ int lcnt[16];
    int t = threadIdx.x, b = blockIdx.x;
    if (t < 16) lcnt[t] = 0;
    __syncthreads();
    int bs = bstart[b], n = bcnt[b];
    for (int i = t; i < n; i += 256) atomicAdd(&lcnt[packed[bs + i] & 15], 1);
    __syncthreads();
    if (t < 16) dinv[b * 16 + t] = rsqrtf((float)(lcnt[t] + 1));  // +1 self loop
}

// ---------------- hws = dinv * (x @ W1) ----------------

__global__ void k_xw1(const float* __restrict__ x, const float* __restrict__ W1,
                      const float* __restrict__ dinv, float* __restrict__ hws) {
    int node = blockIdx.x * blockDim.x + threadIdx.x;
    if (node >= N_NODES) return;
    float acc[16];
#pragma unroll
    for (int h = 0; h < 16; ++h) acc[h] = 0.0f;
    const float4* xr = (const float4*)(x + (long)node * F_IN);
#pragma unroll 2
    for (int k0 = 0; k0 < 32; ++k0) {
        float4 xv = xr[k0];
        float xj[4] = {xv.x, xv.y, xv.z, xv.w};
#pragma unroll
        for (int j = 0; j < 4; ++j) {
            int k = k0 * 4 + j;
#pragma unroll
            for (int h = 0; h < 16; ++h) acc[h] += xj[j] * W1[k * 16 + h];
        }
    }
    float dv = dinv[node];
    float4* o = (float4*)(hws + node * HID);
#pragma unroll
    for (int q = 0; q < 4; ++q)
        o[q] = make_float4(dv * acc[q * 4], dv * acc[q * 4 + 1],
                           dv * acc[q * 4 + 2], dv * acc[q * 4 + 3]);
}

// ---------------- bucket gather: agg[v] = dinv[v]*(sum_in hws[s] + hws[v]) + b ----------------

__global__ void k_bgather(const int* __restrict__ bstart, const int* __restrict__ bcnt,
                          const unsigned int* __restrict__ packed,
                          const float* __restrict__ dinv, const float* __restrict__ hws,
                          const float* __restrict__ bias, float* __restrict__ agg) {
    __shared__ float acc[16][17];
    __shared__ unsigned int stg[256];
    int t = threadIdx.x, b = blockIdx.x;
    int r = t >> 4, f = t & 15;
    int node0 = b * 16;
    acc[r][f] = hws[(node0 + r) * HID + f];  // self-loop term
    int bs = bstart[b], n = bcnt[b];
    for (int base = 0; base < n; base += 256) {
        int m = n - base;
        if (m > 256) m = 256;
        __syncthreads();                       // protect stg reuse + acc init
        if (t < m) stg[t] = packed[bs + base + t];
        __syncthreads();
        for (int sub = 0; sub < m; sub += 16) {
            int es = sub + r;
            if (es < m) {
                unsigned int w = stg[es];
                int s = (int)(w >> 4);
                int dl = (int)(w & 15);
                atomicAdd(&acc[dl][f], hws[s * HID + f]);
            }
        }
    }
    __syncthreads();
    int node = node0 + r;
    agg[node * HID + f] = dinv[node] * acc[r][f] + bias[f];
}

// ---------------- hws2 = dinv * (relu(agg) @ W2) ----------------

__global__ void k_hw2(const float* __restrict__ agg, const float* __restrict__ W2,
                      const float* __restrict__ dinv, float* __restrict__ hws2) {
    __shared__ float w2s[16][17];
    int tid = threadIdx.x;  // 256
    w2s[tid >> 4][tid & 15] = W2[tid];
    __syncthreads();
    int gid = blockIdx.x * 256 + tid;
    if (gid >= N_NODES * HID) return;
    int node = gid >> 4, f = gid & 15;
    float acc = 0.0f;
#pragma unroll
    for (int k = 0; k < 16; ++k) {
        float hv = agg[node * HID + k];
        hv = hv > 0.0f ? hv : 0.0f;
        acc += hv * w2s[k][f];
    }
    hws2[gid] = dinv[node] * acc;
}

// ---------------- t = hd @ predictor ----------------

__global__ void k_t(const float* __restrict__ agg, const float* __restrict__ pred,
                    float* __restrict__ t) {
    __shared__ float ps[256];
    int tid = threadIdx.x;
    ps[tid] = pred[tid];
    __syncthreads();
    int gid = blockIdx.x * 256 + tid;
    if (gid >= N_DRUGS * HID) return;
    int i = gid >> 4, k = gid & 15;
    float acc = 0.0f;
#pragma unroll
    for (int m = 0; m < 16; ++m) acc += agg[i * HID + m] * ps[m * 16 + k];
    t[gid] = acc;
}

// ---------------- out[i][j] = dot(t[i], hd[j]) ----------------

__global__ void k_out(const float* __restrict__ t, const float* __restrict__ agg,
                      float* __restrict__ out) {
    __shared__ float ts[16][17], hs[16][17];
    int tid = threadIdx.x;  // 256
    int li = tid >> 4, lj = tid & 15;
    int i0 = blockIdx.y * 16, j0 = blockIdx.x * 16;
    ts[li][lj] = t[(i0 + li) * HID + lj];
    hs[li][lj] = agg[(j0 + li) * HID + lj];
    __syncthreads();
    float acc = 0.0f;
#pragma unroll
    for (int k = 0; k < 16; ++k) acc += ts[li][k] * hs[lj][k];
    out[(long)(i0 + li) * N_DRUGS + (j0 + lj)] = acc;
}

extern "C" void kernel_launch(void* const* d_in, const int* in_sizes, int n_in,
                              void* d_out, int out_size, void* d_ws, size_t ws_size,
                              hipStream_t stream) {
    const float* x    = (const float*)d_in[0];
    const int*   ei   = (const int*)d_in[1];
    const float* W1   = (const float*)d_in[2];
    const float* b1   = (const float*)d_in[3];
    const float* W2   = (const float*)d_in[4];
    const float* b2   = (const float*)d_in[5];
    const float* pred = (const float*)d_in[6];
    float* out = (float*)d_out;

    const int* src = ei;             // edge_index[0]
    const int* dst = ei + N_EDGES;   // edge_index[1]

    char* w = (char*)d_ws;
    int*   cnt8   = (int*)w;                  w += (size_t)NHIST * 4;
    int*   cur8   = (int*)w;                  w += (size_t)NHIST * 4;
    int*   bstart = (int*)w;                  w += (size_t)NBUCK * 4;
    int*   bcnt   = (int*)w;                  w += (size_t)NBUCK * 4;
    float* dinv   = (float*)w;                w += (size_t)N_NODES * 4;
    unsigned int* packed = (unsigned int*)w;  w += (size_t)N_EDGES * 4;
    float* hws    = (float*)w;                w += (size_t)N_NODES * HID * 4;
    float* agg    = (float*)w;                w += (size_t)N_NODES * HID * 4;
    float* tbuf   = (float*)w;                w += (size_t)N_DRUGS * HID * 4;

    const int B = 256;
    const int EB = (N_EDGES + B - 1) / B;

    // bucket CSR build
    k_zero<<<(NHIST + B - 1) / B, B, 0, stream>>>(cnt8, NHIST);
    k_bhist<<<EB, B, 0, stream>>>(dst, cnt8);
    k_bscan<<<1, 1024, 0, stream>>>(cnt8, cur8);
    k_bmeta<<<(NBUCK + B - 1) / B, B, 0, stream>>>(cnt8, cur8, bstart, bcnt);
    k_bfill<<<EB, B, 0, stream>>>(src, dst, cur8, packed);
    k_bdeg<<<NBUCK, B, 0, stream>>>(bstart, bcnt, packed, dinv);

    // layer 1
    k_xw1<<<NB, B, 0, stream>>>(x, W1, dinv, hws);
    k_bgather<<<NBUCK, B, 0, stream>>>(bstart, bcnt, packed, dinv, hws, b1, agg);

    // layer 2
    k_hw2<<<(N_NODES * HID + B - 1) / B, B, 0, stream>>>(agg, W2, dinv, hws);
    k_bgather<<<NBUCK, B, 0, stream>>>(bstart, bcnt, packed, dinv, hws, b2, agg);

    // readout
    k_t<<<(N_DRUGS * HID + B - 1) / B, B, 0, stream>>>(agg, pred, tbuf);
    dim3 og(N_DRUGS / 16, N_DRUGS / 16);
    k_out<<<og, B, 0, stream>>>(tbuf, agg, out);
}

// Round 10
// 961.669 us; speedup vs baseline: 1.0874x; 1.0874x over previous
//
#include <hip/hip_runtime.h>
#include <hip/hip_bf16.h>

#define N_NODES 100000
#define N_EDGES 3200000
#define F_IN    128
#define HID     16
#define N_DRUGS 2000
#define NB      391             // ceil(N_NODES/256) for xw1
#define NBUCK   782             // ceil(N_NODES/128): 128-node buckets
#define CHUNK   8192            // edges per fill block
#define NCHUNK  391             // ceil(N_EDGES/CHUNK)

// ---------------- zero helper ----------------

__global__ void k_zero(int* __restrict__ p, int n) {
    int i = blockIdx.x * blockDim.x + threadIdx.x;
    if (i < n) p[i] = 0;
}

// ---------------- chunked histogram: cnt[bucket] via LDS ----------------

__global__ void k_chist(const int* __restrict__ dst, int* __restrict__ cnt) {
    __shared__ int lh[NBUCK];
    int t = threadIdx.x;
    int e0 = blockIdx.x * CHUNK;
    int m = N_EDGES - e0; if (m > CHUNK) m = CHUNK;
    for (int i = t; i < NBUCK; i += 256) lh[i] = 0;
    __syncthreads();
    for (int i = t; i < m; i += 256) atomicAdd(&lh[dst[e0 + i] >> 7], 1);
    __syncthreads();
    for (int i = t; i < NBUCK; i += 256) if (lh[i]) atomicAdd(&cnt[i], lh[i]);
}

// ---------------- global scan over 782 buckets (one block) ----------------

__global__ void k_gscan(const int* __restrict__ cnt, int* __restrict__ bstart,
                        int* __restrict__ cur) {
    __shared__ int s[1024];
    int t = threadIdx.x;
    int v = (t < NBUCK) ? cnt[t] : 0;
    s[t] = v;
    __syncthreads();
    for (int off = 1; off < 1024; off <<= 1) {
        int x = (t >= off) ? s[t - off] : 0;
        __syncthreads();
        s[t] += x;
        __syncthreads();
    }
    if (t < NBUCK) { int ex = s[t] - v; bstart[t] = ex; cur[t] = ex; }
}

// ---------------- chunk-binned fill: LDS reorder, run-coalesced writes ----------------

__global__ void k_cfill(const int* __restrict__ src, const int* __restrict__ dst,
                        int* __restrict__ cur, unsigned int* __restrict__ packed) {
    __shared__ int lhist[NBUCK], lscan[NBUCK], runbase[NBUCK], lcur[NBUCK];
    __shared__ int ts[256];
    __shared__ unsigned int stg[CHUNK];
    int t = threadIdx.x;
    int e0 = blockIdx.x * CHUNK;
    int m = N_EDGES - e0; if (m > CHUNK) m = CHUNK;

    for (int i = t; i < NBUCK; i += 256) lhist[i] = 0;
    __syncthreads();
    for (int i = t; i < m; i += 256) atomicAdd(&lhist[dst[e0 + i] >> 7], 1);
    __syncthreads();

    // block-wide exclusive scan of lhist (thread owns 4 contiguous entries)
    int base4 = t * 4;
    int loc[4], tsum = 0;
#pragma unroll
    for (int j = 0; j < 4; ++j) {
        int idx = base4 + j;
        int v = (idx < NBUCK) ? lhist[idx] : 0;
        loc[j] = tsum; tsum += v;
    }
    ts[t] = tsum;
    __syncthreads();
    for (int off = 1; off < 256; off <<= 1) {
        int x = (t >= off) ? ts[t - off] : 0;
        __syncthreads();
        ts[t] += x;
        __syncthreads();
    }
    int tbase = ts[t] - tsum;
#pragma unroll
    for (int j = 0; j < 4; ++j) {
        int idx = base4 + j;
        if (idx < NBUCK) lscan[idx] = tbase + loc[j];
    }
    __syncthreads();

    // reserve global runs, init local cursors
    for (int i = t; i < NBUCK; i += 256) {
        int c = lhist[i];
        runbase[i] = c ? atomicAdd(&cur[i], c) : 0;
        lcur[i] = lscan[i];
    }
    __syncthreads();

    // stage edges bucket-sorted in LDS
    for (int i = t; i < m; i += 256) {
        int d = dst[e0 + i];
        int b = d >> 7;
        int p = atomicAdd(&lcur[b], 1);
        stg[p] = ((unsigned int)src[e0 + i] << 7) | (unsigned int)(d & 127);
    }
    __syncthreads();

    // write out; slot -> bucket via binary search (largest b with lscan[b] <= p)
    for (int p = t; p < m; p += 256) {
        int lo = 0, hi = NBUCK - 1;
        while (lo < hi) {
            int mid = (lo + hi + 1) >> 1;
            if (lscan[mid] <= p) lo = mid; else hi = mid - 1;
        }
        packed[runbase[lo] + (p - lscan[lo])] = stg[p];
    }
}

// ---------------- per-bucket degree -> dinv ----------------

__global__ void k_bdeg(const int* __restrict__ bstart, const int* __restrict__ cnt,
                       const unsigned int* __restrict__ packed, float* __restrict__ dinv) {
    __shared__ int lcnt[128];
    int t = threadIdx.x, b = blockIdx.x;
    if (t < 128) lcnt[t] = 0;
    __syncthreads();
    int bs = bstart[b], n = cnt[b];
    for (int i = t; i < n; i += 256) atomicAdd(&lcnt[packed[bs + i] & 127], 1);
    __syncthreads();
    if (t < 128) {
        int node = b * 128 + t;
        if (node < N_NODES) dinv[node] = rsqrtf((float)(lcnt[t] + 1));  // +1 self loop
    }
}

// ---------------- hws = dinv * (x @ W1) ----------------

__global__ void k_xw1(const float* __restrict__ x, const float* __restrict__ W1,
                      const float* __restrict__ dinv, float* __restrict__ hws) {
    int node = blockIdx.x * blockDim.x + threadIdx.x;
    if (node >= N_NODES) return;
    float acc[16];
#pragma unroll
    for (int h = 0; h < 16; ++h) acc[h] = 0.0f;
    const float4* xr = (const float4*)(x + (long)node * F_IN);
#pragma unroll 2
    for (int k0 = 0; k0 < 32; ++k0) {
        float4 xv = xr[k0];
        float xj[4] = {xv.x, xv.y, xv.z, xv.w};
#pragma unroll
        for (int j = 0; j < 4; ++j) {
            int k = k0 * 4 + j;
#pragma unroll
            for (int h = 0; h < 16; ++h) acc[h] += xj[j] * W1[k * 16 + h];
        }
    }
    float dv = dinv[node];
    float4* o = (float4*)(hws + node * HID);
#pragma unroll
    for (int q = 0; q < 4; ++q)
        o[q] = make_float4(dv * acc[q * 4], dv * acc[q * 4 + 1],
                           dv * acc[q * 4 + 2], dv * acc[q * 4 + 3]);
}

// ---------------- bucket gather, 8-deep load batching ----------------
// agg[v] = dinv[v]*(sum_in hws[s] + hws[v]) + bias

__global__ void k_bgather(const int* __restrict__ bstart, const int* __restrict__ cnt,
                          const unsigned int* __restrict__ packed,
                          const float* __restrict__ dinv, const float* __restrict__ hws,
                          const float* __restrict__ bias, float* __restrict__ agg) {
    __shared__ float acc[128][17];
    __shared__ unsigned int stg[256];
    int t = threadIdx.x, b = blockIdx.x;
    int r = t >> 4, f = t & 15;          // 16 groups of 16 lanes
    int node0 = b * 128;
    for (int row = r; row < 128; row += 16) {
        int node = node0 + row;
        acc[row][f] = (node < N_NODES) ? hws[node * HID + f] : 0.0f;  // self-loop term
    }
    int bs = bstart[b], n = cnt[b];
    for (int base = 0; base < n; base += 256) {
        int m = n - base; if (m > 256) m = 256;
        __syncthreads();                  // acc init / previous stg use complete
        if (t < m) stg[t] = packed[bs + base + t];
        __syncthreads();
#pragma unroll
        for (int k0 = 0; k0 < 16; k0 += 8) {
            float v[8]; int dl[8]; bool ok[8];
#pragma unroll
            for (int u = 0; u < 8; ++u) {
                int es = (k0 + u) * 16 + r;
                ok[u] = es < m;
                unsigned int wv = ok[u] ? stg[es] : 0u;
                int s = (int)(wv >> 7);
                dl[u] = (int)(wv & 127);
                v[u] = ok[u] ? hws[s * HID + f] : 0.0f;   // 8 independent loads in flight
            }
#pragma unroll
            for (int u = 0; u < 8; ++u)
                if (ok[u]) atomicAdd(&acc[dl[u]][f], v[u]);
        }
    }
    __syncthreads();
    for (int row = r; row < 128; row += 16) {
        int node = node0 + row;
        if (node < N_NODES) agg[node * HID + f] = dinv[node] * acc[row][f] + bias[f];
    }
}

// ---------------- hws2 = dinv * (relu(agg) @ W2) ----------------

__global__ void k_hw2(const float* __restrict__ agg, const float* __restrict__ W2,
                      const float* __restrict__ dinv, float* __restrict__ hws2) {
    __shared__ float w2s[16][17];
    int tid = threadIdx.x;  // 256
    w2s[tid >> 4][tid & 15] = W2[tid];
    __syncthreads();
    int gid = blockIdx.x * 256 + tid;
    if (gid >= N_NODES * HID) return;
    int node = gid >> 4, f = gid & 15;
    float acc = 0.0f;
#pragma unroll
    for (int k = 0; k < 16; ++k) {
        float hv = agg[node * HID + k];
        hv = hv > 0.0f ? hv : 0.0f;
        acc += hv * w2s[k][f];
    }
    hws2[gid] = dinv[node] * acc;
}

// ---------------- t = hd @ predictor ----------------

__global__ void k_t(const float* __restrict__ agg, const float* __restrict__ pred,
                    float* __restrict__ t) {
    __shared__ float ps[256];
    int tid = threadIdx.x;
    ps[tid] = pred[tid];
    __syncthreads();
    int gid = blockIdx.x * 256 + tid;
    if (gid >= N_DRUGS * HID) return;
    int i = gid >> 4, k = gid & 15;
    float acc = 0.0f;
#pragma unroll
    for (int m = 0; m < 16; ++m) acc += agg[i * HID + m] * ps[m * 16 + k];
    t[gid] = acc;
}

// ---------------- out[i][j] = dot(t[i], hd[j]) ----------------

__global__ void k_out(const float* __restrict__ t, const float* __restrict__ agg,
                      float* __restrict__ out) {
    __shared__ float ts[16][17], hs[16][17];
    int tid = threadIdx.x;  // 256
    int li = tid >> 4, lj = tid & 15;
    int i0 = blockIdx.y * 16, j0 = blockIdx.x * 16;
    ts[li][lj] = t[(i0 + li) * HID + lj];
    hs[li][lj] = agg[(j0 + li) * HID + lj];
    __syncthreads();
    float acc = 0.0f;
#pragma unroll
    for (int k = 0; k < 16; ++k) acc += ts[li][k] * hs[lj][k];
    out[(long)(i0 + li) * N_DRUGS + (j0 + lj)] = acc;
}

extern "C" void kernel_launch(void* const* d_in, const int* in_sizes, int n_in,
                              void* d_out, int out_size, void* d_ws, size_t ws_size,
                              hipStream_t stream) {
    const float* x    = (const float*)d_in[0];
    const int*   ei   = (const int*)d_in[1];
    const float* W1   = (const float*)d_in[2];
    const float* b1   = (const float*)d_in[3];
    const float* W2   = (const float*)d_in[4];
    const float* b2   = (const float*)d_in[5];
    const float* pred = (const float*)d_in[6];
    float* out = (float*)d_out;

    const int* src = ei;             // edge_index[0]
    const int* dst = ei + N_EDGES;   // edge_index[1]

    char* w = (char*)d_ws;
    int*   cnt    = (int*)w;                  w += (size_t)NBUCK * 4;
    int*   bstart = (int*)w;                  w += (size_t)NBUCK * 4;
    int*   cur    = (int*)w;                  w += (size_t)NBUCK * 4;
    float* dinv   = (float*)w;                w += (size_t)N_NODES * 4;
    unsigned int* packed = (unsigned int*)w;  w += (size_t)N_EDGES * 4;
    float* hws    = (float*)w;                w += (size_t)N_NODES * HID * 4;
    float* agg    = (float*)w;                w += (size_t)N_NODES * HID * 4;
    float* tbuf   = (float*)w;                w += (size_t)N_DRUGS * HID * 4;

    const int B = 256;

    // bucket CSR build (chunk-binned)
    k_zero<<<(NBUCK + B - 1) / B, B, 0, stream>>>(cnt, NBUCK);
    k_chist<<<NCHUNK, B, 0, stream>>>(dst, cnt);
    k_gscan<<<1, 1024, 0, stream>>>(cnt, bstart, cur);
    k_cfill<<<NCHUNK, B, 0, stream>>>(src, dst, cur, packed);
    k_bdeg<<<NBUCK, B, 0, stream>>>(bstart, cnt, packed, dinv);

    // layer 1
    k_xw1<<<NB, B, 0, stream>>>(x, W1, dinv, hws);
    k_bgather<<<NBUCK, B, 0, stream>>>(bstart, cnt, packed, dinv, hws, b1, agg);

    // layer 2
    k_hw2<<<(N_NODES * HID + B - 1) / B, B, 0, stream>>>(agg, W2, dinv, hws);
    k_bgather<<<NBUCK, B, 0, stream>>>(bstart, cnt, packed, dinv, hws, b2, agg);

    // readout
    k_t<<<(N_DRUGS * HID + B - 1) / B, B, 0, stream>>>(agg, pred, tbuf);
    dim3 og(N_DRUGS / 16, N_DRUGS / 16);
    k_out<<<og, B, 0, stream>>>(tbuf, agg, out);
}

// Round 11
// 341.858 us; speedup vs baseline: 3.0589x; 2.8131x over previous
//
#include <hip/hip_runtime.h>
#include <hip/hip_bf16.h>

#define N_NODES 100000
#define N_EDGES 3200000
#define F_IN    128
#define HID     16
#define N_DRUGS 2000
#define NB      391             // ceil(N_NODES/256) for xw1
#define NBUCK   782             // ceil(N_NODES/128): 128-node buckets
#define CHUNK   8192            // edges per fill block
#define NCHUNK  391             // ceil(N_EDGES/CHUNK)

// ---------------- zero helper ----------------

__global__ void k_zero(int* __restrict__ p, int n) {
    int i = blockIdx.x * blockDim.x + threadIdx.x;
    if (i < n) p[i] = 0;
}

// ---------------- chunked histogram: cnt[bucket] via LDS ----------------

__global__ void k_chist(const int* __restrict__ dst, int* __restrict__ cnt) {
    __shared__ int lh[NBUCK];
    int t = threadIdx.x;
    int e0 = blockIdx.x * CHUNK;
    int m = N_EDGES - e0; if (m > CHUNK) m = CHUNK;
    for (int i = t; i < NBUCK; i += 256) lh[i] = 0;
    __syncthreads();
    for (int i = t; i < m; i += 256) atomicAdd(&lh[dst[e0 + i] >> 7], 1);
    __syncthreads();
    for (int i = t; i < NBUCK; i += 256) if (lh[i]) atomicAdd(&cnt[i], lh[i]);
}

// ---------------- global scan over 782 buckets (one block) ----------------

__global__ void k_gscan(const int* __restrict__ cnt, int* __restrict__ bstart,
                        int* __restrict__ cur) {
    __shared__ int s[1024];
    int t = threadIdx.x;
    int v = (t < NBUCK) ? cnt[t] : 0;
    s[t] = v;
    __syncthreads();
    for (int off = 1; off < 1024; off <<= 1) {
        int x = (t >= off) ? s[t - off] : 0;
        __syncthreads();
        s[t] += x;
        __syncthreads();
    }
    if (t < NBUCK) { int ex = s[t] - v; bstart[t] = ex; cur[t] = ex; }
    if (t == 0) bstart[NBUCK] = N_EDGES;  // sentinel
}

// ---------------- chunk-binned fill: LDS reorder, run-coalesced writes ----------------

__global__ void k_cfill(const int* __restrict__ src, const int* __restrict__ dst,
                        int* __restrict__ cur, unsigned int* __restrict__ packed) {
    __shared__ int lhist[NBUCK], lscan[NBUCK], runbase[NBUCK], lcur[NBUCK];
    __shared__ int ts[256];
    __shared__ unsigned int stg[CHUNK];
    int t = threadIdx.x;
    int e0 = blockIdx.x * CHUNK;
    int m = N_EDGES - e0; if (m > CHUNK) m = CHUNK;

    for (int i = t; i < NBUCK; i += 256) lhist[i] = 0;
    __syncthreads();
    for (int i = t; i < m; i += 256) atomicAdd(&lhist[dst[e0 + i] >> 7], 1);
    __syncthreads();

    // block-wide exclusive scan of lhist (thread owns 4 contiguous entries)
    int base4 = t * 4;
    int loc[4], tsum = 0;
#pragma unroll
    for (int j = 0; j < 4; ++j) {
        int idx = base4 + j;
        int v = (idx < NBUCK) ? lhist[idx] : 0;
        loc[j] = tsum; tsum += v;
    }
    ts[t] = tsum;
    __syncthreads();
    for (int off = 1; off < 256; off <<= 1) {
        int x = (t >= off) ? ts[t - off] : 0;
        __syncthreads();
        ts[t] += x;
        __syncthreads();
    }
    int tbase = ts[t] - tsum;
#pragma unroll
    for (int j = 0; j < 4; ++j) {
        int idx = base4 + j;
        if (idx < NBUCK) lscan[idx] = tbase + loc[j];
    }
    __syncthreads();

    // reserve global runs, init local cursors
    for (int i = t; i < NBUCK; i += 256) {
        int c = lhist[i];
        runbase[i] = c ? atomicAdd(&cur[i], c) : 0;
        lcur[i] = lscan[i];
    }
    __syncthreads();

    // stage edges bucket-sorted in LDS
    for (int i = t; i < m; i += 256) {
        int d = dst[e0 + i];
        int b = d >> 7;
        int p = atomicAdd(&lcur[b], 1);
        stg[p] = ((unsigned int)src[e0 + i] << 7) | (unsigned int)(d & 127);
    }
    __syncthreads();

    // write out; slot -> bucket via binary search (largest b with lscan[b] <= p)
    for (int p = t; p < m; p += 256) {
        int lo = 0, hi = NBUCK - 1;
        while (lo < hi) {
            int mid = (lo + hi + 1) >> 1;
            if (lscan[mid] <= p) lo = mid; else hi = mid - 1;
        }
        packed[runbase[lo] + (p - lscan[lo])] = stg[p];
    }
}

// ---------------- per-bucket counting sort -> exact CSR + rowStart + dinv ----------------

__global__ void k_sort(const int* __restrict__ bstart, const unsigned int* __restrict__ packed,
                       int* __restrict__ rowStart, int* __restrict__ csr,
                       float* __restrict__ dinv) {
    __shared__ int lcnt[128], lscan[128], lcur[128];
    __shared__ int s[256];
    int t = threadIdx.x, b = blockIdx.x;
    int bs = bstart[b], n = bstart[b + 1] - bs;
    if (t < 128) lcnt[t] = 0;
    __syncthreads();
    for (int i = t; i < n; i += 256) atomicAdd(&lcnt[packed[bs + i] & 127], 1);
    __syncthreads();
    int v = (t < 128) ? lcnt[t] : 0;
    s[t] = v;
    __syncthreads();
    for (int off = 1; off < 256; off <<= 1) {
        int x = (t >= off) ? s[t - off] : 0;
        __syncthreads();
        s[t] += x;
        __syncthreads();
    }
    if (t < 128) {
        int ex = s[t] - v;
        lscan[t] = ex;
        lcur[t] = ex;
        int node = b * 128 + t;
        if (node < N_NODES) {
            rowStart[node] = bs + ex;
            dinv[node] = rsqrtf((float)(v + 1));  // +1 self loop
        }
    }
    if (b == NBUCK - 1 && t == 0) rowStart[N_NODES] = N_EDGES;
    __syncthreads();
    for (int i = t; i < n; i += 256) {
        unsigned int w = packed[bs + i];
        int pos = atomicAdd(&lcur[w & 127], 1);
        csr[bs + pos] = (int)(w >> 7);
    }
}

// ---------------- hws = dinv * (x @ W1) ----------------

__global__ void k_xw1(const float* __restrict__ x, const float* __restrict__ W1,
                      const float* __restrict__ dinv, float* __restrict__ hws) {
    int node = blockIdx.x * blockDim.x + threadIdx.x;
    if (node >= N_NODES) return;
    float acc[16];
#pragma unroll
    for (int h = 0; h < 16; ++h) acc[h] = 0.0f;
    const float4* xr = (const float4*)(x + (long)node * F_IN);
#pragma unroll 2
    for (int k0 = 0; k0 < 32; ++k0) {
        float4 xv = xr[k0];
        float xj[4] = {xv.x, xv.y, xv.z, xv.w};
#pragma unroll
        for (int j = 0; j < 4; ++j) {
            int k = k0 * 4 + j;
#pragma unroll
            for (int h = 0; h < 16; ++h) acc[h] += xj[j] * W1[k * 16 + h];
        }
    }
    float dv = dinv[node];
    float4* o = (float4*)(hws + node * HID);
#pragma unroll
    for (int q = 0; q < 4; ++q)
        o[q] = make_float4(dv * acc[q * 4], dv * acc[q * 4 + 1],
                           dv * acc[q * 4 + 2], dv * acc[q * 4 + 3]);
}

// ---------------- exact-CSR gather, register accumulation, 8-deep ILP ----------------
// agg[v] = dinv[v]*(sum_in hws[s] + hws[v]) + bias

__global__ void k_gather2(const int* __restrict__ rowStart, const int* __restrict__ csr,
                          const float* __restrict__ dinv, const float* __restrict__ hws,
                          const float* __restrict__ bias, float* __restrict__ agg) {
    int t = threadIdx.x;
    int g = t >> 4, f = t & 15;            // 16 lane-groups x 16 features
    int node = blockIdx.x * 16 + g;
    if (node >= N_NODES) return;
    int row = rowStart[node], end = rowStart[node + 1];
    float acc = hws[node * HID + f];       // self-loop term
    int j = row;
    for (; j + 8 <= end; j += 8) {
        float v0 = hws[csr[j + 0] * HID + f];
        float v1 = hws[csr[j + 1] * HID + f];
        float v2 = hws[csr[j + 2] * HID + f];
        float v3 = hws[csr[j + 3] * HID + f];
        float v4 = hws[csr[j + 4] * HID + f];
        float v5 = hws[csr[j + 5] * HID + f];
        float v6 = hws[csr[j + 6] * HID + f];
        float v7 = hws[csr[j + 7] * HID + f];
        acc += ((v0 + v1) + (v2 + v3)) + ((v4 + v5) + (v6 + v7));
    }
    for (; j < end; ++j) acc += hws[csr[j] * HID + f];
    agg[node * HID + f] = dinv[node] * acc + bias[f];
}

// ---------------- hws2 = dinv * (relu(agg) @ W2) ----------------

__global__ void k_hw2(const float* __restrict__ agg, const float* __restrict__ W2,
                      const float* __restrict__ dinv, float* __restrict__ hws2) {
    __shared__ float w2s[16][17];
    int tid = threadIdx.x;  // 256
    w2s[tid >> 4][tid & 15] = W2[tid];
    __syncthreads();
    int gid = blockIdx.x * 256 + tid;
    if (gid >= N_NODES * HID) return;
    int node = gid >> 4, f = gid & 15;
    float acc = 0.0f;
#pragma unroll
    for (int k = 0; k < 16; ++k) {
        float hv = agg[node * HID + k];
        hv = hv > 0.0f ? hv : 0.0f;
        acc += hv * w2s[k][f];
    }
    hws2[gid] = dinv[node] * acc;
}

// ---------------- t = hd @ predictor ----------------

__global__ void k_t(const float* __restrict__ agg, const float* __restrict__ pred,
                    float* __restrict__ t) {
    __shared__ float ps[256];
    int tid = threadIdx.x;
    ps[tid] = pred[tid];
    __syncthreads();
    int gid = blockIdx.x * 256 + tid;
    if (gid >= N_DRUGS * HID) return;
    int i = gid >> 4, k = gid & 15;
    float acc = 0.0f;
#pragma unroll
    for (int m = 0; m < 16; ++m) acc += agg[i * HID + m] * ps[m * 16 + k];
    t[gid] = acc;
}

// ---------------- out[i][j] = dot(t[i], hd[j]) ----------------

__global__ void k_out(const float* __restrict__ t, const float* __restrict__ agg,
                      float* __restrict__ out) {
    __shared__ float ts[16][17], hs[16][17];
    int tid = threadIdx.x;  // 256
    int li = tid >> 4, lj = tid & 15;
    int i0 = blockIdx.y * 16, j0 = blockIdx.x * 16;
    ts[li][lj] = t[(i0 + li) * HID + lj];
    hs[li][lj] = agg[(j0 + li) * HID + lj];
    __syncthreads();
    float acc = 0.0f;
#pragma unroll
    for (int k = 0; k < 16; ++k) acc += ts[li][k] * hs[lj][k];
    out[(long)(i0 + li) * N_DRUGS + (j0 + lj)] = acc;
}

extern "C" void kernel_launch(void* const* d_in, const int* in_sizes, int n_in,
                              void* d_out, int out_size, void* d_ws, size_t ws_size,
                              hipStream_t stream) {
    const float* x    = (const float*)d_in[0];
    const int*   ei   = (const int*)d_in[1];
    const float* W1   = (const float*)d_in[2];
    const float* b1   = (const float*)d_in[3];
    const float* W2   = (const float*)d_in[4];
    const float* b2   = (const float*)d_in[5];
    const float* pred = (const float*)d_in[6];
    float* out = (float*)d_out;

    const int* src = ei;             // edge_index[0]
    const int* dst = ei + N_EDGES;   // edge_index[1]

    char* w = (char*)d_ws;
    int*   cnt      = (int*)w;                w += (size_t)NBUCK * 4;
    int*   bstart   = (int*)w;                w += (size_t)(NBUCK + 1) * 4;
    int*   cur      = (int*)w;                w += (size_t)NBUCK * 4;
    int*   rowStart = (int*)w;                w += (size_t)(N_NODES + 1) * 4;
    float* dinv     = (float*)w;              w += (size_t)N_NODES * 4;
    unsigned int* packed = (unsigned int*)w;  w += (size_t)N_EDGES * 4;
    int*   csr      = (int*)w;                w += (size_t)N_EDGES * 4;
    float* hws      = (float*)w;              w += (size_t)N_NODES * HID * 4;
    float* agg      = (float*)w;              w += (size_t)N_NODES * HID * 4;
    float* tbuf     = (float*)w;              w += (size_t)N_DRUGS * HID * 4;

    const int B = 256;

    // exact CSR build: chunk-bin to 128-node buckets, then per-bucket counting sort
    k_zero<<<(NBUCK + B - 1) / B, B, 0, stream>>>(cnt, NBUCK);
    k_chist<<<NCHUNK, B, 0, stream>>>(dst, cnt);
    k_gscan<<<1, 1024, 0, stream>>>(cnt, bstart, cur);
    k_cfill<<<NCHUNK, B, 0, stream>>>(src, dst, cur, packed);
    k_sort<<<NBUCK, B, 0, stream>>>(bstart, packed, rowStart, csr, dinv);

    // layer 1
    k_xw1<<<NB, B, 0, stream>>>(x, W1, dinv, hws);
    k_gather2<<<(N_NODES + 15) / 16, B, 0, stream>>>(rowStart, csr, dinv, hws, b1, agg);

    // layer 2
    k_hw2<<<(N_NODES * HID + B - 1) / B, B, 0, stream>>>(agg, W2, dinv, hws);
    k_gather2<<<(N_NODES + 15) / 16, B, 0, stream>>>(rowStart, csr, dinv, hws, b2, agg);

    // readout
    k_t<<<(N_DRUGS * HID + B - 1) / B, B, 0, stream>>>(agg, pred, tbuf);
    dim3 og(N_DRUGS / 16, N_DRUGS / 16);
    k_out<<<og, B, 0, stream>>>(tbuf, agg, out);
}

// Round 12
// 300.300 us; speedup vs baseline: 3.4823x; 1.1384x over previous
//
#include <hip/hip_runtime.h>
#include <hip/hip_bf16.h>

#define N_NODES 100000
#define N_EDGES 3200000
#define F_IN    128
#define HID     16
#define N_DRUGS 2000
#define NB      391             // ceil(N_NODES/256) for xw1
#define NBUCK   782             // ceil(N_NODES/128): 128-node buckets
#define CHUNK   8192            // edges per fill block
#define NCHUNK  391             // ceil(N_EDGES/CHUNK)

// ---------------- zero helper ----------------

__global__ void k_zero(int* __restrict__ p, int n) {
    int i = blockIdx.x * blockDim.x + threadIdx.x;
    if (i < n) p[i] = 0;
}

// ---------------- chunked histogram: cnt[bucket] via LDS (1024 thr) ----------------

__global__ void k_chist(const int* __restrict__ dst, int* __restrict__ cnt) {
    __shared__ int lh[NBUCK];
    int t = threadIdx.x;
    int e0 = blockIdx.x * CHUNK;
    int m = N_EDGES - e0; if (m > CHUNK) m = CHUNK;
    for (int i = t; i < NBUCK; i += 1024) lh[i] = 0;
    __syncthreads();
    for (int i = t; i < m; i += 1024) atomicAdd(&lh[dst[e0 + i] >> 7], 1);
    __syncthreads();
    for (int i = t; i < NBUCK; i += 1024) if (lh[i]) atomicAdd(&cnt[i], lh[i]);
}

// ---------------- global scan over 782 buckets (one block) ----------------

__global__ void k_gscan(const int* __restrict__ cnt, int* __restrict__ bstart,
                        int* __restrict__ cur) {
    __shared__ int s[1024];
    int t = threadIdx.x;
    int v = (t < NBUCK) ? cnt[t] : 0;
    s[t] = v;
    __syncthreads();
    for (int off = 1; off < 1024; off <<= 1) {
        int x = (t >= off) ? s[t - off] : 0;
        __syncthreads();
        s[t] += x;
        __syncthreads();
    }
    if (t < NBUCK) { int ex = s[t] - v; bstart[t] = ex; cur[t] = ex; }
    if (t == 0) bstart[NBUCK] = N_EDGES;  // sentinel
}

// ---------------- chunk-binned fill: 1024 thr, LDS reorder, no binary search ----
// smem carve (ints): lhist[782] lscan[782] runbase[782] lcur[782]
//                    stg[8192] (scan temp s[1024] aliases its head)
//                    sbuck[8192 u16] = 4096 ints  -> total 15416 ints = 61.7 KB

__global__ void k_cfill(const int* __restrict__ src, const int* __restrict__ dst,
                        int* __restrict__ cur, unsigned int* __restrict__ packed) {
    __shared__ int smem[15416];
    int* lhist   = smem;
    int* lscan   = smem + NBUCK;
    int* runbase = smem + 2 * NBUCK;
    int* lcur    = smem + 3 * NBUCK;
    int* stg     = smem + 4 * NBUCK;          // 8192 ints (scan temp aliases head)
    int* s       = stg;                        // 1024 ints, used only pre-staging
    unsigned short* sbuck = (unsigned short*)(smem + 4 * NBUCK + CHUNK);  // 8192 u16

    int t = threadIdx.x;  // 1024
    int e0 = blockIdx.x * CHUNK;
    int m = N_EDGES - e0; if (m > CHUNK) m = CHUNK;

    for (int i = t; i < NBUCK; i += 1024) lhist[i] = 0;
    __syncthreads();
    for (int i = t; i < m; i += 1024) atomicAdd(&lhist[dst[e0 + i] >> 7], 1);
    __syncthreads();

    // exclusive scan of lhist over 1024 lanes (NBUCK=782 < 1024)
    int v = (t < NBUCK) ? lhist[t] : 0;
    s[t] = v;
    __syncthreads();
    for (int off = 1; off < 1024; off <<= 1) {
        int x = (t >= off) ? s[t - off] : 0;
        __syncthreads();
        s[t] += x;
        __syncthreads();
    }
    if (t < NBUCK) lscan[t] = s[t] - v;
    __syncthreads();   // scan temp dead after this; stg reusable

    // reserve global runs, init local cursors
    for (int i = t; i < NBUCK; i += 1024) {
        int c = lhist[i];
        runbase[i] = c ? atomicAdd(&cur[i], c) : 0;
        lcur[i] = lscan[i];
    }
    __syncthreads();

    // stage edges bucket-sorted in LDS; record bucket id
    for (int i = t; i < m; i += 1024) {
        int d = dst[e0 + i];
        int b = d >> 7;
        int p = atomicAdd(&lcur[b], 1);
        stg[p] = (int)(((unsigned int)src[e0 + i] << 7) | (unsigned int)(d & 127));
        sbuck[p] = (unsigned short)b;
    }
    __syncthreads();

    // write out: run-coalesced, 2 LDS reads per edge
    for (int p = t; p < m; p += 1024) {
        int b = (int)sbuck[p];
        packed[runbase[b] + (p - lscan[b])] = (unsigned int)stg[p];
    }
}

// ---------------- per-bucket counting sort -> exact CSR + rowStart + dinv ----------------

__global__ void k_sort(const int* __restrict__ bstart, const unsigned int* __restrict__ packed,
                       int* __restrict__ rowStart, int* __restrict__ csr,
                       float* __restrict__ dinv) {
    __shared__ int lcnt[128], lscan[128], lcur[128];
    __shared__ int s[256];
    int t = threadIdx.x, b = blockIdx.x;
    int bs = bstart[b], n = bstart[b + 1] - bs;
    if (t < 128) lcnt[t] = 0;
    __syncthreads();
    for (int i = t; i < n; i += 256) atomicAdd(&lcnt[packed[bs + i] & 127], 1);
    __syncthreads();
    int v = (t < 128) ? lcnt[t] : 0;
    s[t] = v;
    __syncthreads();
    for (int off = 1; off < 256; off <<= 1) {
        int x = (t >= off) ? s[t - off] : 0;
        __syncthreads();
        s[t] += x;
        __syncthreads();
    }
    if (t < 128) {
        int ex = s[t] - v;
        lscan[t] = ex;
        lcur[t] = ex;
        int node = b * 128 + t;
        if (node < N_NODES) {
            rowStart[node] = bs + ex;
            dinv[node] = rsqrtf((float)(v + 1));  // +1 self loop
        }
    }
    if (b == NBUCK - 1 && t == 0) rowStart[N_NODES] = N_EDGES;
    __syncthreads();
    for (int i = t; i < n; i += 256) {
        unsigned int w = packed[bs + i];
        int pos = atomicAdd(&lcur[w & 127], 1);
        csr[bs + pos] = (int)(w >> 7);
    }
}

// ---------------- hws = dinv * (x @ W1) ----------------

__global__ void k_xw1(const float* __restrict__ x, const float* __restrict__ W1,
                      const float* __restrict__ dinv, float* __restrict__ hws) {
    int node = blockIdx.x * blockDim.x + threadIdx.x;
    if (node >= N_NODES) return;
    float acc[16];
#pragma unroll
    for (int h = 0; h < 16; ++h) acc[h] = 0.0f;
    const float4* xr = (const float4*)(x + (long)node * F_IN);
#pragma unroll 2
    for (int k0 = 0; k0 < 32; ++k0) {
        float4 xv = xr[k0];
        float xj[4] = {xv.x, xv.y, xv.z, xv.w};
#pragma unroll
        for (int j = 0; j < 4; ++j) {
            int k = k0 * 4 + j;
#pragma unroll
            for (int h = 0; h < 16; ++h) acc[h] += xj[j] * W1[k * 16 + h];
        }
    }
    float dv = dinv[node];
    float4* o = (float4*)(hws + node * HID);
#pragma unroll
    for (int q = 0; q < 4; ++q)
        o[q] = make_float4(dv * acc[q * 4], dv * acc[q * 4 + 1],
                           dv * acc[q * 4 + 2], dv * acc[q * 4 + 3]);
}

// ---------------- exact-CSR gather, register accumulation, 8-deep ILP ----------------
// agg[v] = dinv[v]*(sum_in hws[s] + hws[v]) + bias

__global__ void k_gather2(const int* __restrict__ rowStart, const int* __restrict__ csr,
                          const float* __restrict__ dinv, const float* __restrict__ hws,
                          const float* __restrict__ bias, float* __restrict__ agg) {
    int t = threadIdx.x;
    int g = t >> 4, f = t & 15;            // 16 lane-groups x 16 features
    int node = blockIdx.x * 16 + g;
    if (node >= N_NODES) return;
    int row = rowStart[node], end = rowStart[node + 1];
    float acc = hws[node * HID + f];       // self-loop term
    int j = row;
    for (; j + 8 <= end; j += 8) {
        float v0 = hws[csr[j + 0] * HID + f];
        float v1 = hws[csr[j + 1] * HID + f];
        float v2 = hws[csr[j + 2] * HID + f];
        float v3 = hws[csr[j + 3] * HID + f];
        float v4 = hws[csr[j + 4] * HID + f];
        float v5 = hws[csr[j + 5] * HID + f];
        float v6 = hws[csr[j + 6] * HID + f];
        float v7 = hws[csr[j + 7] * HID + f];
        acc += ((v0 + v1) + (v2 + v3)) + ((v4 + v5) + (v6 + v7));
    }
    for (; j < end; ++j) acc += hws[csr[j] * HID + f];
    agg[node * HID + f] = dinv[node] * acc + bias[f];
}

// ---------------- hws2 = dinv * (relu(agg) @ W2) ----------------

__global__ void k_hw2(const float* __restrict__ agg, const float* __restrict__ W2,
                      const float* __restrict__ dinv, float* __restrict__ hws2) {
    __shared__ float w2s[16][17];
    int tid = threadIdx.x;  // 256
    w2s[tid >> 4][tid & 15] = W2[tid];
    __syncthreads();
    int gid = blockIdx.x * 256 + tid;
    if (gid >= N_NODES * HID) return;
    int node = gid >> 4, f = gid & 15;
    float acc = 0.0f;
#pragma unroll
    for (int k = 0; k < 16; ++k) {
        float hv = agg[node * HID + k];
        hv = hv > 0.0f ? hv : 0.0f;
        acc += hv * w2s[k][f];
    }
    hws2[gid] = dinv[node] * acc;
}

// ---------------- t = hd @ predictor ----------------

__global__ void k_t(const float* __restrict__ agg, const float* __restrict__ pred,
                    float* __restrict__ t) {
    __shared__ float ps[256];
    int tid = threadIdx.x;
    ps[tid] = pred[tid];
    __syncthreads();
    int gid = blockIdx.x * 256 + tid;
    if (gid >= N_DRUGS * HID) return;
    int i = gid >> 4, k = gid & 15;
    float acc = 0.0f;
#pragma unroll
    for (int m = 0; m < 16; ++m) acc += agg[i * HID + m] * ps[m * 16 + k];
    t[gid] = acc;
}

// ---------------- out[i][j] = dot(t[i], hd[j]) ----------------

__global__ void k_out(const float* __restrict__ t, const float* __restrict__ agg,
                      float* __restrict__ out) {
    __shared__ float ts[16][17], hs[16][17];
    int tid = threadIdx.x;  // 256
    int li = tid >> 4, lj = tid & 15;
    int i0 = blockIdx.y * 16, j0 = blockIdx.x * 16;
    ts[li][lj] = t[(i0 + li) * HID + lj];
    hs[li][lj] = agg[(j0 + li) * HID + lj];
    __syncthreads();
    float acc = 0.0f;
#pragma unroll
    for (int k = 0; k < 16; ++k) acc += ts[li][k] * hs[lj][k];
    out[(long)(i0 + li) * N_DRUGS + (j0 + lj)] = acc;
}

extern "C" void kernel_launch(void* const* d_in, const int* in_sizes, int n_in,
                              void* d_out, int out_size, void* d_ws, size_t ws_size,
                              hipStream_t stream) {
    const float* x    = (const float*)d_in[0];
    const int*   ei   = (const int*)d_in[1];
    const float* W1   = (const float*)d_in[2];
    const float* b1   = (const float*)d_in[3];
    const float* W2   = (const float*)d_in[4];
    const float* b2   = (const float*)d_in[5];
    const float* pred = (const float*)d_in[6];
    float* out = (float*)d_out;

    const int* src = ei;             // edge_index[0]
    const int* dst = ei + N_EDGES;   // edge_index[1]

    char* w = (char*)d_ws;
    int*   cnt      = (int*)w;                w += (size_t)NBUCK * 4;
    int*   bstart   = (int*)w;                w += (size_t)(NBUCK + 1) * 4;
    int*   cur      = (int*)w;                w += (size_t)NBUCK * 4;
    int*   rowStart = (int*)w;                w += (size_t)(N_NODES + 1) * 4;
    float* dinv     = (float*)w;              w += (size_t)N_NODES * 4;
    unsigned int* packed = (unsigned int*)w;  w += (size_t)N_EDGES * 4;
    int*   csr      = (int*)w;                w += (size_t)N_EDGES * 4;
    float* hws      = (float*)w;              w += (size_t)N_NODES * HID * 4;
    float* agg      = (float*)w;              w += (size_t)N_NODES * HID * 4;
    float* tbuf     = (float*)w;              w += (size_t)N_DRUGS * HID * 4;

    const int B = 256;

    // exact CSR build: chunk-bin to 128-node buckets, then per-bucket counting sort
    k_zero<<<(NBUCK + B - 1) / B, B, 0, stream>>>(cnt, NBUCK);
    k_chist<<<NCHUNK, 1024, 0, stream>>>(dst, cnt);
    k_gscan<<<1, 1024, 0, stream>>>(cnt, bstart, cur);
    k_cfill<<<NCHUNK, 1024, 0, stream>>>(src, dst, cur, packed);
    k_sort<<<NBUCK, B, 0, stream>>>(bstart, packed, rowStart, csr, dinv);

    // layer 1
    k_xw1<<<NB, B, 0, stream>>>(x, W1, dinv, hws);
    k_gather2<<<(N_NODES + 15) / 16, B, 0, stream>>>(rowStart, csr, dinv, hws, b1, agg);

    // layer 2
    k_hw2<<<(N_NODES * HID + B - 1) / B, B, 0, stream>>>(agg, W2, dinv, hws);
    k_gather2<<<(N_NODES + 15) / 16, B, 0, stream>>>(rowStart, csr, dinv, hws, b2, agg);

    // readout
    k_t<<<(N_DRUGS * HID + B - 1) / B, B, 0, stream>>>(agg, pred, tbuf);
    dim3 og(N_DRUGS / 16, N_DRUGS / 16);
    k_out<<<og, B, 0, stream>>>(tbuf, agg, out);
}